// Round 13
// baseline (285.990 us; speedup 1.0000x reference)
//
#include <hip/hip_runtime.h>
#include <hip/hip_bf16.h>

typedef __attribute__((ext_vector_type(8))) short bf16x8;
typedef __attribute__((ext_vector_type(4))) float f32x4;

union U8 { uint4 u; bf16x8 v; };

// ---------- bf16 helpers ----------
__device__ __forceinline__ float bf2f(unsigned short u) {
    return __uint_as_float(((unsigned)u) << 16);
}
__device__ __forceinline__ unsigned short f2bf(float f) {
    unsigned u = __float_as_uint(f);
    u += 0x7fffu + ((u >> 16) & 1u);
    return (unsigned short)(u >> 16);
}
__device__ __forceinline__ unsigned pk2bf(float a, float b) {
    __hip_bfloat162 h = __float22bfloat162_rn(make_float2(a, b));
    union { __hip_bfloat162 h; unsigned u; } cv; cv.h = h; return cv.u;
}
__device__ __forceinline__ void unpack8(uint4 u, float* f) {
    f[0] = __uint_as_float(u.x << 16); f[1] = __uint_as_float(u.x & 0xffff0000u);
    f[2] = __uint_as_float(u.y << 16); f[3] = __uint_as_float(u.y & 0xffff0000u);
    f[4] = __uint_as_float(u.z << 16); f[5] = __uint_as_float(u.z & 0xffff0000u);
    f[6] = __uint_as_float(u.w << 16); f[7] = __uint_as_float(u.w & 0xffff0000u);
}

struct Ptrs { const unsigned short* p[22]; };

__device__ __forceinline__ float loadEl(const unsigned short* p, long i, int f32) {
    return f32 ? ((const float*)p)[i] : bf2f(p[i]);
}

// fp32 scalar region (element offsets in wb)
constexpr int OFF_B1 = 5184;
constexpr int OFF_B2 = 60672;
constexpr int OFF_B3 = 88416;
constexpr int OFF_BO = 89376;

// bf16 tables (ushort offsets in wf)
constexpr int OFFW1A = 0;
constexpr int OFFW1B = 6144;
constexpr int OFFW2 = 12288;
constexpr int OFFW3 = 67584;
constexpr int OFFWO = 95232;
constexpr int OFFBT = 99840;    // biasT bf16 [4 cls][64 j(key)][64 i(query)], x log2e

constexpr int H2SZ = 9437184;   // u16 elems per branch ([2][147456][32])

// flag detection: sample 2048 even u16s of x
__device__ __forceinline__ int detect_f32(const unsigned short* x) {
    __shared__ int cnt;
    if (threadIdx.x == 0) cnt = 0;
    __syncthreads();
    int crazy = 0;
    for (int i = threadIdx.x; i < 2048; i += 256) {
        unsigned short u = x[2 * i];
        int e = (u >> 7) & 0xFF;
        if (e >= 0x90) crazy++;
    }
    atomicAdd(&cnt, crazy);
    __syncthreads();
    return (cnt > 32) ? 1 : 0;
}

// ---------- prep (grid 1024; computes dtype flag per block) ----------
__global__ __launch_bounds__(256) void prep_kern(Ptrs in, float* wb, unsigned short* wf,
                                                 unsigned short* xc, int* flagOut) {
    const int f32 = detect_f32(in.p[0]);
    if (blockIdx.x == 0 && threadIdx.x == 0) *flagOut = f32;
    int tid = blockIdx.x * 256 + threadIdx.x;
    int nth = gridDim.x * 256;
    for (int i = tid; i < 192; i += nth) wb[OFF_B1 + i] = loadEl(in.p[2 + 6 * (i / 64)], i % 64, f32);
    for (int i = tid; i < 96;  i += nth) wb[OFF_B2 + i] = loadEl(in.p[4 + 6 * (i / 32)], i % 32, f32);
    for (int i = tid; i < 96;  i += nth) wb[OFF_B3 + i] = loadEl(in.p[6 + 6 * (i / 32)], i % 32, f32);
    for (int i = tid; i < 3;   i += nth) wb[OFF_BO + i] = loadEl(in.p[20], i, f32);
    // biasT bf16, scaled by log2(e); masks baked
    for (int i = tid; i < 16384; i += nth) {
        int cls = i >> 12, rem = i & 4095, j = rem >> 6, qi = rem & 63;
        int ih = qi >> 3, iw = qi & 7, jh = j >> 3, jw = j & 7;
        float v = loadEl(in.p[21], (jh - ih + 7) * 15 + (jw - iw + 7), f32) * 1.4426950408889634f;
        if ((cls & 1) && ((ih >= 4) != (jh >= 4))) v = -1e30f;
        if ((cls & 2) && ((iw >= 4) != (jw >= 4))) v = -1e30f;
        wf[OFFBT + i] = f2bf(v);
    }
    // wf1A: taps 0..7; lane l: n = 4*(l&15)+nt, k -> tap=2q+(j>>2), cin=j&3
    for (int i = tid; i < 3 * 2048; i += nth) {
        int br = i / 2048, r = i % 2048;
        int nt = r / 512, rr = r % 512, lane = rr >> 3, j = rr & 7;
        int qq = lane >> 4, n = 4 * (lane & 15) + nt;
        int tap = 2 * qq + (j >> 2), cin = j & 3;
        float v = (cin < 3) ? loadEl(in.p[1 + 6 * br], n * 27 + cin * 9 + tap, f32) : 0.f;
        wf[OFFW1A + i] = f2bf(v);
    }
    // wf1B: tap 8 only
    for (int i = tid; i < 3 * 2048; i += nth) {
        int br = i / 2048, r = i % 2048;
        int nt = r / 512, rr = r % 512, lane = rr >> 3, j = rr & 7;
        int qq = lane >> 4, n = 4 * (lane & 15) + nt;
        float v = (qq == 0 && j < 3) ? loadEl(in.p[1 + 6 * br], n * 27 + j * 9 + 8, f32) : 0.f;
        wf[OFFW1B + i] = f2bf(v);
    }
    // wf2: conv2 (K=576=tap*64+cin, N=32), n = 2*m+nt
    for (int i = tid; i < 3 * 18432; i += nth) {
        int br = i / 18432, r = i % 18432;
        int frag = r / 512, rr = r % 512, lane = rr >> 3, j = rr & 7;
        int s = frag >> 1, nt = frag & 1;
        int k = s * 32 + ((lane >> 4) << 3) + j, n = 2 * (lane & 15) + nt;
        int cin = k & 63, tap = k >> 6;
        wf[OFFW2 + i] = f2bf(loadEl(in.p[3 + 6 * br], n * 576 + cin * 9 + tap, f32));
    }
    // wf3: conv3 (K=288=tap*32+cin, N=32), n = 2*m+nt
    for (int i = tid; i < 3 * 9216; i += nth) {
        int br = i / 9216, r = i % 9216;
        int frag = r / 512, rr = r % 512, lane = rr >> 3, j = rr & 7;
        int s = frag >> 1, nt = frag & 1;
        int k = s * 32 + ((lane >> 4) << 3) + j, n = 2 * (lane & 15) + nt;
        int cin = k & 31, tap = k >> 5;
        wf[OFFW3 + i] = f2bf(loadEl(in.p[5 + 6 * br], n * 288 + cin * 9 + tap, f32));
    }
    // wfO
    for (int i = tid; i < 4608; i += nth) {
        int frag = i / 512, rr = i % 512, lane = rr >> 3, j = rr & 7;
        int k = frag * 32 + ((lane >> 4) << 3) + j, n = lane & 15;
        float v = (n < 3) ? loadEl(in.p[19], n * 288 + (k & 31) * 9 + (k >> 5), f32) : 0.f;
        wf[OFFWO + i] = f2bf(v);
    }
    // xc: NHWC pad4, pixel per thread
    for (int i = tid; i < 294912; i += nth) {
        int b = i / 147456, hw = i % 147456;
        float v0 = loadEl(in.p[0], (long)(b * 3 + 0) * 147456 + hw, f32);
        float v1 = loadEl(in.p[0], (long)(b * 3 + 1) * 147456 + hw, f32);
        float v2 = loadEl(in.p[0], (long)(b * 3 + 2) * 147456 + hw, f32);
        uint2 pk;
        pk.x = pk2bf(v0, v1);
        pk.y = pk2bf(v2, 0.f);
        *(uint2*)(&xc[(size_t)i * 4]) = pk;
    }
}

// ---------- fused conv1+conv2, branch-merged: sX + conv1 A-frags shared by 3 brs ----------
__global__ __launch_bounds__(256) void conv12_mfma(
    const unsigned short* __restrict__ xc, const unsigned short* __restrict__ wf,
    const float* __restrict__ wb, unsigned short* __restrict__ h2all) {
    __shared__ __align__(16) unsigned short sX[6][68][4];
    __shared__ __align__(16) unsigned short sH1[264 * 64];
    const int b = blockIdx.z;
    const int h0 = blockIdx.y * 2, w0 = blockIdx.x * 64;
    const int tid = threadIdx.x;
    for (int idx = tid; idx < 408; idx += 256) {
        int col = idx % 68, row = idx / 68;
        int gh = h0 + row - 2, gw = w0 + col - 2;
        uint2 v = make_uint2(0, 0);
        if ((unsigned)gh < 384u && (unsigned)gw < 384u)
            v = *(const uint2*)(xc + ((size_t)(b * 147456 + gh * 384 + gw) << 2));
        *(uint2*)(&sX[row][col][0]) = v;
    }
    __syncthreads();
    const int lane = tid & 63, wave = tid >> 6;
    const int mcol = lane & 15, q = lane >> 4;
    const int tA0 = 2 * q, tA1 = 2 * q + 1;
    const int khA0 = (tA0 * 11) >> 5, kwA0 = tA0 - khA0 * 3;
    const int khA1 = (tA1 * 11) >> 5, kwA1 = tA1 - khA1 * 3;
    // ---- phase A: build conv1 A-frags once (branch-independent) ----
    bf16x8 ua[5], ub[5];
#pragma unroll
    for (int s = 0; s < 5; ++s) {
        int t = wave + s * 4;
        if (t < 17) {
            int p = t * 16 + mcol; int pcl = p < 263 ? p : 263;
            int r1 = (pcl * 993) >> 16, c1 = pcl - r1 * 66;
            uint2 pa = *(const uint2*)&sX[r1 + khA0][c1 + kwA0][0];
            uint2 pb = *(const uint2*)&sX[r1 + khA1][c1 + kwA1][0];
            uint2 pc2 = *(const uint2*)&sX[r1 + 2][c1 + 2][0];
            U8 x1; x1.u = make_uint4(pa.x, pa.y, pb.x, pb.y);
            U8 x2; x2.u = make_uint4(pc2.x, pc2.y, 0u, 0u);
            ua[s] = x1.v; ub[s] = x2.v;
        }
    }
    // ---- phase B: per branch conv1 -> sH1 -> conv2 -> h2 ----
    for (int br = 0; br < 3; ++br) {
        const unsigned short* wf1a = wf + OFFW1A + br * 2048;
        const unsigned short* wf1b = wf + OFFW1B + br * 2048;
        const unsigned short* wf2 = wf + OFFW2 + br * 18432;
        {
            float bn[4];
            bf16x8 wA[4], wB[4];
#pragma unroll
            for (int nt = 0; nt < 4; ++nt) {
                bn[nt] = wb[OFF_B1 + br * 64 + 4 * mcol + nt];
                wA[nt] = *(const bf16x8*)(wf1a + nt * 512 + lane * 8);
                wB[nt] = *(const bf16x8*)(wf1b + nt * 512 + lane * 8);
            }
#pragma unroll
            for (int s = 0; s < 5; ++s) {
                int t = wave + s * 4;
                if (t < 17) {
                    f32x4 acc[4];
#pragma unroll
                    for (int nt = 0; nt < 4; ++nt) {
                        acc[nt] = f32x4{bn[nt], bn[nt], bn[nt], bn[nt]};
                        acc[nt] = __builtin_amdgcn_mfma_f32_16x16x32_bf16(ua[s], wA[nt], acc[nt], 0, 0, 0);
                        acc[nt] = __builtin_amdgcn_mfma_f32_16x16x32_bf16(ub[s], wB[nt], acc[nt], 0, 0, 0);
                    }
#pragma unroll
                    for (int r = 0; r < 4; ++r) {
                        int p2 = t * 16 + q * 4 + r;
                        if (p2 < 264) {
                            int r2 = (p2 * 993) >> 16, c2 = p2 - r2 * 66;
                            unsigned lo = pk2bf(fmaxf(acc[0][r], 0.f), fmaxf(acc[1][r], 0.f));
                            unsigned hi = pk2bf(fmaxf(acc[2][r], 0.f), fmaxf(acc[3][r], 0.f));
                            bool inb = ((unsigned)(h0 - 1 + r2) < 384u) && ((unsigned)(w0 - 1 + c2) < 384u);
                            if (!inb) { lo = 0u; hi = 0u; }
                            int seg = (mcol >> 1) ^ (p2 & 7);
                            *(uint2*)(&sH1[p2 * 64 + seg * 8 + ((mcol & 1) << 2)]) = make_uint2(lo, hi);
                        }
                    }
                }
            }
        }
        __syncthreads();
        f32x4 acc0[2], acc1[2];
        {
            float b0 = wb[OFF_B2 + br * 32 + 2 * mcol], b1 = wb[OFF_B2 + br * 32 + 2 * mcol + 1];
#pragma unroll
            for (int hr = 0; hr < 2; ++hr) {
                acc0[hr] = f32x4{b0, b0, b0, b0};
                acc1[hr] = f32x4{b1, b1, b1, b1};
            }
        }
        for (int kh = 0; kh < 3; ++kh) {
            const unsigned short* wbase = wf2 + kh * 6 * 1024 + lane * 8;
#pragma unroll
            for (int u = 0; u < 6; ++u) {
                const int kw = u >> 1, segl = (u & 1) * 4 + q;
                bf16x8 bf0 = *(const bf16x8*)(wbase + u * 1024);
                bf16x8 bf1 = *(const bf16x8*)(wbase + u * 1024 + 512);
#pragma unroll
                for (int hr = 0; hr < 2; ++hr) {
                    int p = (kh + hr) * 66 + wave * 16 + mcol + kw;
                    int seg = segl ^ (p & 7);
                    bf16x8 a = *(const bf16x8*)(&sH1[p * 64 + seg * 8]);
                    acc0[hr] = __builtin_amdgcn_mfma_f32_16x16x32_bf16(a, bf0, acc0[hr], 0, 0, 0);
                    acc1[hr] = __builtin_amdgcn_mfma_f32_16x16x32_bf16(a, bf1, acc1[hr], 0, 0, 0);
                }
            }
        }
        unsigned short* h2 = h2all + (size_t)br * H2SZ;
#pragma unroll
        for (int hr = 0; hr < 2; ++hr) {
            size_t base = (size_t)(b * 147456 + (h0 + hr) * 384 + w0 + wave * 16 + q * 4) * 32 + 2 * mcol;
#pragma unroll
            for (int r = 0; r < 4; ++r)
                *(unsigned*)(&h2[base + (size_t)r * 32]) =
                    pk2bf(fmaxf(acc0[hr][r], 0.f), fmaxf(acc1[hr][r], 0.f));
        }
        if (br < 2) __syncthreads();   // sH1 reused by next branch
    }
}

// ---------- conv3: 32->32, LDS staged, writes qkv [b][win][tok][32]; Q pre-scaled ----------
__global__ __launch_bounds__(256) void conv3_mfma(
    const unsigned short* __restrict__ h2all, const unsigned short* __restrict__ wf,
    const float* __restrict__ wb, unsigned short* __restrict__ qkvAll) {
    __shared__ __align__(16) unsigned short sIn[6][66][40];
    const int z = blockIdx.z, br = z >> 1, b = z & 1;
    const int h0 = blockIdx.y * 4, w0 = blockIdx.x * 64;
    const int tid = threadIdx.x;
    const unsigned short* in = h2all + (size_t)br * H2SZ;
    const unsigned short* wf3 = wf + OFFW3 + br * 9216;
    unsigned short* qkv = qkvAll + (size_t)br * H2SZ;
    for (int idx = tid; idx < 1584; idx += 256) {
        int seg = idx & 3, t = idx >> 2, col = t % 66, kr = t / 66;
        int gh = h0 + kr - 1, gw = w0 + col - 1;
        uint4 v = make_uint4(0, 0, 0, 0);
        if ((unsigned)gh < 384u && (unsigned)gw < 384u)
            v = *(const uint4*)(in + ((size_t)(b * 147456 + gh * 384 + gw) << 5) + seg * 8);
        *(uint4*)(&sIn[kr][col][seg * 8]) = v;
    }
    __syncthreads();
    const int lane = tid & 63, wave = tid >> 6;
    const int mcol = lane & 15, q = lane >> 4;
    const float scale = (br == 0) ? 0.51006973f : 1.0f;   // 8^-0.5 * log2e folded into Q
    f32x4 acc0[4], acc1[4];
    {
        float b0 = wb[OFF_B3 + br * 32 + 2 * mcol], b1 = wb[OFF_B3 + br * 32 + 2 * mcol + 1];
#pragma unroll
        for (int hr = 0; hr < 4; ++hr) {
            acc0[hr] = f32x4{b0, b0, b0, b0};
            acc1[hr] = f32x4{b1, b1, b1, b1};
        }
    }
    for (int kh = 0; kh < 3; ++kh) {
        const unsigned short* wbase = wf3 + kh * 3 * 1024 + lane * 8;
#pragma unroll
        for (int u = 0; u < 3; ++u) {
            bf16x8 bf0 = *(const bf16x8*)(wbase + u * 1024);
            bf16x8 bf1 = *(const bf16x8*)(wbase + u * 1024 + 512);
#pragma unroll
            for (int hr = 0; hr < 4; ++hr) {
                bf16x8 a = *(const bf16x8*)(&sIn[kh + hr][wave * 16 + mcol + u][q * 8]);
                acc0[hr] = __builtin_amdgcn_mfma_f32_16x16x32_bf16(a, bf0, acc0[hr], 0, 0, 0);
                acc1[hr] = __builtin_amdgcn_mfma_f32_16x16x32_bf16(a, bf1, acc1[hr], 0, 0, 0);
            }
        }
    }
#pragma unroll
    for (int hr = 0; hr < 4; ++hr) {
        int sh = h0 + hr - 4; if (sh < 0) sh += 384;
#pragma unroll
        for (int r = 0; r < 4; ++r) {
            int w = w0 + wave * 16 + q * 4 + r;
            int sw = w - 4; if (sw < 0) sw += 384;
            int win = (sh >> 3) * 48 + (sw >> 3);
            int tok = (sh & 7) * 8 + (sw & 7);
            size_t tb = ((size_t)(b * 2304 + win) * 64 + tok) * 32;
            *(unsigned*)(&qkv[tb + 2 * mcol]) = pk2bf(acc0[hr][r] * scale, acc1[hr][r] * scale);
        }
    }
}

// ---------- MFMA windowed attention: block=(win,b), wave=head (r10 version) ----------
__global__ __launch_bounds__(256) void attn_mfma(
    const unsigned short* __restrict__ Qp, const unsigned short* __restrict__ Kp,
    const unsigned short* __restrict__ Vp, const unsigned short* __restrict__ biasTb,
    unsigned short* __restrict__ att) {
    __shared__ __align__(16) unsigned short sVT[4][16][72];  // [head][dim(8=ones)][key]
    __shared__ __align__(16) unsigned short sPm[4][16][72];  // [head][q-row][key]
    __shared__ __align__(16) unsigned short sOut[64][40];    // [tok][ch32]
    const int win = blockIdx.x, b = blockIdx.y;
    const int wr = win / 48, wc = win % 48;
    const int tid = threadIdx.x;
    const int lane = tid & 63, head = tid >> 6;
    const size_t wbase = (size_t)(b * 2304 + win) * 64;
    {
        int tok = lane;
        uint4 v = *(const uint4*)(Vp + (wbase + tok) * 32 + head * 8);
        unsigned short d[8];
        d[0] = (unsigned short)v.x; d[1] = (unsigned short)(v.x >> 16);
        d[2] = (unsigned short)v.y; d[3] = (unsigned short)(v.y >> 16);
        d[4] = (unsigned short)v.z; d[5] = (unsigned short)(v.z >> 16);
        d[6] = (unsigned short)v.w; d[7] = (unsigned short)(v.w >> 16);
#pragma unroll
        for (int dd = 0; dd < 8; ++dd) sVT[head][dd][tok] = d[dd];
        sVT[head][8][tok] = 0x3f80;   // 1.0 (ones column -> rowsum)
#pragma unroll
        for (int dd = 9; dd < 16; ++dd) sVT[head][dd][tok] = 0;
    }
    const int mcol = lane & 15, q = lane >> 4;
    const int cls = (wr == 47 ? 1 : 0) + (wc == 47 ? 2 : 0);
    const unsigned short* bT = biasTb + cls * 4096;
    const bf16x8 zero8 = {0, 0, 0, 0, 0, 0, 0, 0};
    bf16x8 kb[4];
#pragma unroll
    for (int nt = 0; nt < 4; ++nt)
        kb[nt] = (q == 0) ? *(const bf16x8*)(Kp + (wbase + nt * 16 + mcol) * 32 + head * 8) : zero8;
    bf16x8 vb0 = *(const bf16x8*)(&sVT[head][mcol][q * 8]);
    bf16x8 vb1 = *(const bf16x8*)(&sVT[head][mcol][32 + q * 8]);
#pragma unroll
    for (int mt = 0; mt < 4; ++mt) {
        bf16x8 qa = (q == 0) ? *(const bf16x8*)(Qp + (wbase + mt * 16 + mcol) * 32 + head * 8) : zero8;
        f32x4 s[4];
#pragma unroll
        for (int nt = 0; nt < 4; ++nt) {
            const ushort4 bb = *(const ushort4*)(bT + (nt * 16 + mcol) * 64 + mt * 16 + q * 4);
            s[nt] = f32x4{bf2f(bb.x), bf2f(bb.y), bf2f(bb.z), bf2f(bb.w)};
            s[nt] = __builtin_amdgcn_mfma_f32_16x16x32_bf16(qa, kb[nt], s[nt], 0, 0, 0);
        }
#pragma unroll
        for (int nt = 0; nt < 4; ++nt)
#pragma unroll
            for (int r = 0; r < 4; ++r) {
                float p = exp2f(fminf(s[nt][r], 86.f));  // masked bias -1e30 -> 0
                sPm[head][q * 4 + r][nt * 16 + mcol] = f2bf(p);
            }
        bf16x8 ap0 = *(const bf16x8*)(&sPm[head][mcol][q * 8]);
        bf16x8 ap1 = *(const bf16x8*)(&sPm[head][mcol][32 + q * 8]);
        f32x4 o = {0.f, 0.f, 0.f, 0.f};
        o = __builtin_amdgcn_mfma_f32_16x16x32_bf16(ap0, vb0, o, 0, 0, 0);
        o = __builtin_amdgcn_mfma_f32_16x16x32_bf16(ap1, vb1, o, 0, 0, 0);
#pragma unroll
        for (int r = 0; r < 4; ++r) {
            float sum = __shfl(o[r], (lane & 48) + 8, 64);
            float val = o[r] / sum;
            if (mcol < 8) {
                int tok = mt * 16 + q * 4 + r;
                sOut[tok][head * 8 + mcol] = f2bf(val);
            }
        }
    }
    __syncthreads();   // cross-wave: sOut columns come from all 4 heads
    {
        int tok = tid >> 2, seg = tid & 3;
        int ihh = tok >> 3, iww = tok & 7;
        int px = (wr * 8 + ihh) * 384 + wc * 8 + iww;
        uint4 pk = *(const uint4*)(&sOut[tok][seg * 8]);
        *(uint4*)(att + (((size_t)(b * 147456 + px)) << 5) + seg * 8) = pk;
    }
}

// ---------- out conv MFMA (shifted space, NHWC32 in) + inverse roll + residual ----------
__global__ __launch_bounds__(256) void outconv_mfma(
    const unsigned short* __restrict__ att, const unsigned short* __restrict__ x_raw,
    const unsigned short* __restrict__ wf, const float* __restrict__ wb,
    void* __restrict__ outp, const int* __restrict__ flagp) {
    __shared__ __align__(16) unsigned short sIn[6][66][40];
    const int f32 = *flagp;
    const int b = blockIdx.z, h0 = blockIdx.y * 4, w0 = blockIdx.x * 64;
    const int tid = threadIdx.x;
    for (int idx = tid; idx < 1584; idx += 256) {
        int seg = idx & 3, t = idx >> 2, col = t % 66, kr = t / 66;
        int gh = h0 + kr - 1, gw = w0 + col - 1;
        uint4 v = make_uint4(0, 0, 0, 0);
        if ((unsigned)gh < 384u && (unsigned)gw < 384u)
            v = *(const uint4*)(att + ((size_t)(b * 147456 + gh * 384 + gw) << 5) + seg * 8);
        *(uint4*)(&sIn[kr][col][seg * 8]) = v;
    }
    __syncthreads();
    const int lane = tid & 63, wave = tid >> 6;
    const int mcol = lane & 15, q = lane >> 4;
    float bn = (mcol < 3) ? wb[OFF_BO + mcol] : 0.f;
    f32x4 acc[4];
#pragma unroll
    for (int hr = 0; hr < 4; ++hr) acc[hr] = f32x4{bn, bn, bn, bn};
    for (int kh = 0; kh < 3; ++kh) {
        const unsigned short* wbase = wf + kh * 3 * 512 + lane * 8;
#pragma unroll
        for (int u = 0; u < 3; ++u) {
            bf16x8 bf = *(const bf16x8*)(wbase + u * 512);
#pragma unroll
            for (int hr = 0; hr < 4; ++hr) {
                bf16x8 a = *(const bf16x8*)(&sIn[kh + hr][wave * 16 + mcol + u][q * 8]);
                acc[hr] = __builtin_amdgcn_mfma_f32_16x16x32_bf16(a, bf, acc[hr], 0, 0, 0);
            }
        }
    }
    if (mcol < 3) {
#pragma unroll
        for (int hr = 0; hr < 4; ++hr) {
            int oh = h0 + hr + 4; if (oh >= 384) oh -= 384;
#pragma unroll
            for (int r = 0; r < 4; ++r) {
                int w = w0 + wave * 16 + q * 4 + r;
                int ow = w + 4; if (ow >= 384) ow -= 384;
                long idx = (long)(b * 3 + mcol) * 147456 + oh * 384 + ow;
                float xv = loadEl(x_raw, idx, f32);
                float o = acc[hr][r] + xv;
                if (f32) ((float*)outp)[idx] = o;
                else ((unsigned short*)outp)[idx] = f2bf(o);
            }
        }
    }
}

extern "C" void kernel_launch(void* const* d_in, const int* in_sizes, int n_in,
                              void* d_out, int out_size, void* d_ws, size_t ws_size,
                              hipStream_t stream) {
    Ptrs P;
    for (int i = 0; i < 22; ++i) P.p[i] = (const unsigned short*)d_in[i];
    const unsigned short* x_raw = (const unsigned short*)d_in[0];

    char* ws = (char*)d_ws;
    float* wb = (float*)ws;
    int* flag = (int*)(ws + 448 * 1024);
    unsigned short* wf = (unsigned short*)(ws + 512 * 1024);
    unsigned short* xc = (unsigned short*)(ws + 1024 * 1024);
    unsigned short* h2all = (unsigned short*)(ws + 3670016);          // 3 br x 18.9MB
    unsigned short* qkvAll = (unsigned short*)(ws + 3670016 + (size_t)3 * H2SZ * 2);
    unsigned short* att = h2all;   // alias: h2 dead after conv3

    prep_kern<<<dim3(1024), dim3(256), 0, stream>>>(P, wb, wf, xc, flag);
    conv12_mfma<<<dim3(6, 192, 2), dim3(256), 0, stream>>>(xc, wf, wb, h2all);
    conv3_mfma<<<dim3(6, 96, 6), dim3(256), 0, stream>>>(h2all, wf, wb, qkvAll);
    attn_mfma<<<dim3(2304, 2), dim3(256), 0, stream>>>(
        qkvAll, qkvAll + H2SZ, qkvAll + 2 * (size_t)H2SZ, wf + OFFBT, att);
    outconv_mfma<<<dim3(6, 96, 2), dim3(256), 0, stream>>>(att, x_raw, wf + OFFWO,
                                                           wb, d_out, flag);
}

// Round 14
// 261.318 us; speedup vs baseline: 1.0944x; 1.0944x over previous
//
#include <hip/hip_runtime.h>
#include <hip/hip_bf16.h>

typedef __attribute__((ext_vector_type(8))) short bf16x8;
typedef __attribute__((ext_vector_type(4))) float f32x4;

union U8 { uint4 u; bf16x8 v; };

// ---------- bf16 helpers ----------
__device__ __forceinline__ float bf2f(unsigned short u) {
    return __uint_as_float(((unsigned)u) << 16);
}
__device__ __forceinline__ unsigned short f2bf(float f) {
    unsigned u = __float_as_uint(f);
    u += 0x7fffu + ((u >> 16) & 1u);
    return (unsigned short)(u >> 16);
}
__device__ __forceinline__ unsigned pk2bf(float a, float b) {
    __hip_bfloat162 h = __float22bfloat162_rn(make_float2(a, b));
    union { __hip_bfloat162 h; unsigned u; } cv; cv.h = h; return cv.u;
}

struct Ptrs { const unsigned short* p[22]; };

__device__ __forceinline__ float loadEl(const unsigned short* p, long i, int f32) {
    return f32 ? ((const float*)p)[i] : bf2f(p[i]);
}

// fp32 scalar region (element offsets in wb)
constexpr int OFF_B1 = 5184;
constexpr int OFF_B2 = 60672;
constexpr int OFF_B3 = 88416;
constexpr int OFF_BO = 89376;

// bf16 tables (ushort offsets in wf)
constexpr int OFFW1A = 0;
constexpr int OFFW1B = 6144;
constexpr int OFFW2 = 12288;
constexpr int OFFW3 = 67584;
constexpr int OFFWO = 95232;
constexpr int OFFBT = 99840;    // biasT bf16 [4 cls][64 j(key)][64 i(query)], x log2e

constexpr int H2SZ = 9437184;   // u16 elems per branch ([2][147456][32])

// flag detection: sample 2048 even u16s of x
__device__ __forceinline__ int detect_f32(const unsigned short* x) {
    __shared__ int cnt;
    if (threadIdx.x == 0) cnt = 0;
    __syncthreads();
    int crazy = 0;
    for (int i = threadIdx.x; i < 2048; i += 256) {
        unsigned short u = x[2 * i];
        int e = (u >> 7) & 0xFF;
        if (e >= 0x90) crazy++;
    }
    atomicAdd(&cnt, crazy);
    __syncthreads();
    return (cnt > 32) ? 1 : 0;
}

// ---------- prep (grid 1024; computes dtype flag per block) ----------
__global__ __launch_bounds__(256) void prep_kern(Ptrs in, float* wb, unsigned short* wf,
                                                 unsigned short* xc, int* flagOut) {
    const int f32 = detect_f32(in.p[0]);
    if (blockIdx.x == 0 && threadIdx.x == 0) *flagOut = f32;
    int tid = blockIdx.x * 256 + threadIdx.x;
    int nth = gridDim.x * 256;
    for (int i = tid; i < 192; i += nth) wb[OFF_B1 + i] = loadEl(in.p[2 + 6 * (i / 64)], i % 64, f32);
    for (int i = tid; i < 96;  i += nth) wb[OFF_B2 + i] = loadEl(in.p[4 + 6 * (i / 32)], i % 32, f32);
    for (int i = tid; i < 96;  i += nth) wb[OFF_B3 + i] = loadEl(in.p[6 + 6 * (i / 32)], i % 32, f32);
    for (int i = tid; i < 3;   i += nth) wb[OFF_BO + i] = loadEl(in.p[20], i, f32);
    // biasT bf16, scaled by log2(e); masks baked
    for (int i = tid; i < 16384; i += nth) {
        int cls = i >> 12, rem = i & 4095, j = rem >> 6, qi = rem & 63;
        int ih = qi >> 3, iw = qi & 7, jh = j >> 3, jw = j & 7;
        float v = loadEl(in.p[21], (jh - ih + 7) * 15 + (jw - iw + 7), f32) * 1.4426950408889634f;
        if ((cls & 1) && ((ih >= 4) != (jh >= 4))) v = -1e30f;
        if ((cls & 2) && ((iw >= 4) != (jw >= 4))) v = -1e30f;
        wf[OFFBT + i] = f2bf(v);
    }
    // wf1A: taps 0..7; lane l: n = 4*(l&15)+nt, k -> tap=2q+(j>>2), cin=j&3
    for (int i = tid; i < 3 * 2048; i += nth) {
        int br = i / 2048, r = i % 2048;
        int nt = r / 512, rr = r % 512, lane = rr >> 3, j = rr & 7;
        int qq = lane >> 4, n = 4 * (lane & 15) + nt;
        int tap = 2 * qq + (j >> 2), cin = j & 3;
        float v = (cin < 3) ? loadEl(in.p[1 + 6 * br], n * 27 + cin * 9 + tap, f32) : 0.f;
        wf[OFFW1A + i] = f2bf(v);
    }
    // wf1B: tap 8 only
    for (int i = tid; i < 3 * 2048; i += nth) {
        int br = i / 2048, r = i % 2048;
        int nt = r / 512, rr = r % 512, lane = rr >> 3, j = rr & 7;
        int qq = lane >> 4, n = 4 * (lane & 15) + nt;
        float v = (qq == 0 && j < 3) ? loadEl(in.p[1 + 6 * br], n * 27 + j * 9 + 8, f32) : 0.f;
        wf[OFFW1B + i] = f2bf(v);
    }
    // wf2: conv2 (K=576=tap*64+cin, N=32), n = 2*m+nt
    for (int i = tid; i < 3 * 18432; i += nth) {
        int br = i / 18432, r = i % 18432;
        int frag = r / 512, rr = r % 512, lane = rr >> 3, j = rr & 7;
        int s = frag >> 1, nt = frag & 1;
        int k = s * 32 + ((lane >> 4) << 3) + j, n = 2 * (lane & 15) + nt;
        int cin = k & 63, tap = k >> 6;
        wf[OFFW2 + i] = f2bf(loadEl(in.p[3 + 6 * br], n * 576 + cin * 9 + tap, f32));
    }
    // wf3: conv3 (K=288=tap*32+cin, N=32), n = 2*m+nt
    for (int i = tid; i < 3 * 9216; i += nth) {
        int br = i / 9216, r = i % 9216;
        int frag = r / 512, rr = r % 512, lane = rr >> 3, j = rr & 7;
        int s = frag >> 1, nt = frag & 1;
        int k = s * 32 + ((lane >> 4) << 3) + j, n = 2 * (lane & 15) + nt;
        int cin = k & 31, tap = k >> 5;
        wf[OFFW3 + i] = f2bf(loadEl(in.p[5 + 6 * br], n * 288 + cin * 9 + tap, f32));
    }
    // wfO
    for (int i = tid; i < 4608; i += nth) {
        int frag = i / 512, rr = i % 512, lane = rr >> 3, j = rr & 7;
        int k = frag * 32 + ((lane >> 4) << 3) + j, n = lane & 15;
        float v = (n < 3) ? loadEl(in.p[19], n * 288 + (k & 31) * 9 + (k >> 5), f32) : 0.f;
        wf[OFFWO + i] = f2bf(v);
    }
    // xc: NHWC pad4, pixel per thread
    for (int i = tid; i < 294912; i += nth) {
        int b = i / 147456, hw = i % 147456;
        float v0 = loadEl(in.p[0], (long)(b * 3 + 0) * 147456 + hw, f32);
        float v1 = loadEl(in.p[0], (long)(b * 3 + 1) * 147456 + hw, f32);
        float v2 = loadEl(in.p[0], (long)(b * 3 + 2) * 147456 + hw, f32);
        uint2 pk;
        pk.x = pk2bf(v0, v1);
        pk.y = pk2bf(v2, 0.f);
        *(uint2*)(&xc[(unsigned)i * 4u]) = pk;
    }
}

// ---------- fused conv1+conv2, XOR-swizzled sH1 (r10) + 32-bit addr + edge fast path ----------
__global__ __launch_bounds__(256) void conv12_mfma(
    const unsigned short* __restrict__ xc, const unsigned short* __restrict__ wf,
    const float* __restrict__ wb, unsigned short* __restrict__ h2all) {
    __shared__ __align__(16) unsigned short sX[6][68][4];
    __shared__ __align__(16) unsigned short sH1[264 * 64];
    const int z = blockIdx.z, br = z >> 1, b = z & 1;
    const int h0 = blockIdx.y * 2, w0 = blockIdx.x * 64;
    const int tid = threadIdx.x;
    const bool edge = (h0 == 0) | (h0 == 382) | (w0 == 0) | (w0 == 320);
    const unsigned short* wf1a = wf + OFFW1A + br * 2048;
    const unsigned short* wf1b = wf + OFFW1B + br * 2048;
    const unsigned short* wf2 = wf + OFFW2 + br * 18432;
    for (int idx = tid; idx < 408; idx += 256) {
        int col = idx % 68, row = idx / 68;
        int gh = h0 + row - 2, gw = w0 + col - 2;
        uint2 v = make_uint2(0, 0);
        if ((unsigned)gh < 384u && (unsigned)gw < 384u)
            v = *(const uint2*)(xc + (((unsigned)(b * 147456 + gh * 384 + gw)) << 2));
        *(uint2*)(&sX[row][col][0]) = v;
    }
    __syncthreads();
    const int lane = tid & 63, wave = tid >> 6;
    const int mcol = lane & 15, q = lane >> 4;
    const int tA0 = 2 * q, tA1 = 2 * q + 1;
    const int khA0 = (tA0 * 11) >> 5, kwA0 = tA0 - khA0 * 3;
    const int khA1 = (tA1 * 11) >> 5, kwA1 = tA1 - khA1 * 3;
    {
        float bn[4];
        bf16x8 wA[4], wB[4];
#pragma unroll
        for (int nt = 0; nt < 4; ++nt) {
            bn[nt] = wb[OFF_B1 + br * 64 + 4 * mcol + nt];
            wA[nt] = *(const bf16x8*)(wf1a + nt * 512 + lane * 8);
            wB[nt] = *(const bf16x8*)(wf1b + nt * 512 + lane * 8);
        }
        for (int t = wave; t < 17; t += 4) {
            int p = t * 16 + mcol; int pcl = p < 263 ? p : 263;
            int r1 = (pcl * 993) >> 16, c1 = pcl - r1 * 66;
            uint2 pa = *(const uint2*)&sX[r1 + khA0][c1 + kwA0][0];
            uint2 pb = *(const uint2*)&sX[r1 + khA1][c1 + kwA1][0];
            uint2 pc2 = *(const uint2*)&sX[r1 + 2][c1 + 2][0];
            U8 ua; ua.u = make_uint4(pa.x, pa.y, pb.x, pb.y);
            U8 ub; ub.u = make_uint4(pc2.x, pc2.y, 0u, 0u);
            f32x4 acc[4];
#pragma unroll
            for (int nt = 0; nt < 4; ++nt) {
                acc[nt] = f32x4{bn[nt], bn[nt], bn[nt], bn[nt]};
                acc[nt] = __builtin_amdgcn_mfma_f32_16x16x32_bf16(ua.v, wA[nt], acc[nt], 0, 0, 0);
                acc[nt] = __builtin_amdgcn_mfma_f32_16x16x32_bf16(ub.v, wB[nt], acc[nt], 0, 0, 0);
            }
#pragma unroll
            for (int r = 0; r < 4; ++r) {
                int p2 = t * 16 + q * 4 + r;
                if (p2 < 264) {
                    unsigned lo = pk2bf(fmaxf(acc[0][r], 0.f), fmaxf(acc[1][r], 0.f));
                    unsigned hi = pk2bf(fmaxf(acc[2][r], 0.f), fmaxf(acc[3][r], 0.f));
                    if (edge) {   // block-uniform: only border blocks pay the bounds math
                        int r2 = (p2 * 993) >> 16, c2 = p2 - r2 * 66;
                        bool inb = ((unsigned)(h0 - 1 + r2) < 384u) && ((unsigned)(w0 - 1 + c2) < 384u);
                        if (!inb) { lo = 0u; hi = 0u; }
                    }
                    int seg = (mcol >> 1) ^ (p2 & 7);
                    *(uint2*)(&sH1[p2 * 64 + seg * 8 + ((mcol & 1) << 2)]) = make_uint2(lo, hi);
                }
            }
        }
    }
    __syncthreads();
    f32x4 acc0[2], acc1[2];
    {
        float b0 = wb[OFF_B2 + br * 32 + 2 * mcol], b1 = wb[OFF_B2 + br * 32 + 2 * mcol + 1];
#pragma unroll
        for (int hr = 0; hr < 2; ++hr) {
            acc0[hr] = f32x4{b0, b0, b0, b0};
            acc1[hr] = f32x4{b1, b1, b1, b1};
        }
    }
    for (int kh = 0; kh < 3; ++kh) {
        const unsigned short* wbase = wf2 + kh * 6 * 1024 + lane * 8;
#pragma unroll
        for (int u = 0; u < 6; ++u) {
            const int kw = u >> 1, segl = (u & 1) * 4 + q;
            bf16x8 bf0 = *(const bf16x8*)(wbase + u * 1024);
            bf16x8 bf1 = *(const bf16x8*)(wbase + u * 1024 + 512);
#pragma unroll
            for (int hr = 0; hr < 2; ++hr) {
                int p = (kh + hr) * 66 + wave * 16 + mcol + kw;
                int seg = segl ^ (p & 7);
                bf16x8 a = *(const bf16x8*)(&sH1[p * 64 + seg * 8]);
                acc0[hr] = __builtin_amdgcn_mfma_f32_16x16x32_bf16(a, bf0, acc0[hr], 0, 0, 0);
                acc1[hr] = __builtin_amdgcn_mfma_f32_16x16x32_bf16(a, bf1, acc1[hr], 0, 0, 0);
            }
        }
    }
    unsigned short* h2 = h2all + (size_t)br * H2SZ;
#pragma unroll
    for (int hr = 0; hr < 2; ++hr) {
        unsigned base = (unsigned)(b * 147456 + (h0 + hr) * 384 + w0 + wave * 16 + q * 4) * 32u + 2u * mcol;
#pragma unroll
        for (int r = 0; r < 4; ++r)
            *(unsigned*)(&h2[base + (unsigned)r * 32u]) =
                pk2bf(fmaxf(acc0[hr][r], 0.f), fmaxf(acc1[hr][r], 0.f));
    }
}

// ---------- conv3: 32->32, LDS staged, 32-bit addressing; Q pre-scaled x log2e ----------
__global__ __launch_bounds__(256) void conv3_mfma(
    const unsigned short* __restrict__ h2all, const unsigned short* __restrict__ wf,
    const float* __restrict__ wb, unsigned short* __restrict__ qkvAll) {
    __shared__ __align__(16) unsigned short sIn[6][66][40];
    const int z = blockIdx.z, br = z >> 1, b = z & 1;
    const int h0 = blockIdx.y * 4, w0 = blockIdx.x * 64;
    const int tid = threadIdx.x;
    const unsigned short* in = h2all + (size_t)br * H2SZ;
    const unsigned short* wf3 = wf + OFFW3 + br * 9216;
    unsigned short* qkv = qkvAll + (size_t)br * H2SZ;
    for (int idx = tid; idx < 1584; idx += 256) {
        int seg = idx & 3, t = idx >> 2, col = t % 66, kr = t / 66;
        int gh = h0 + kr - 1, gw = w0 + col - 1;
        uint4 v = make_uint4(0, 0, 0, 0);
        if ((unsigned)gh < 384u && (unsigned)gw < 384u)
            v = *(const uint4*)(in + (((unsigned)(b * 147456 + gh * 384 + gw)) << 5) + seg * 8);
        *(uint4*)(&sIn[kr][col][seg * 8]) = v;
    }
    __syncthreads();
    const int lane = tid & 63, wave = tid >> 6;
    const int mcol = lane & 15, q = lane >> 4;
    const float scale = (br == 0) ? 0.51006973f : 1.0f;   // 8^-0.5 * log2e folded into Q
    f32x4 acc0[4], acc1[4];
    {
        float b0 = wb[OFF_B3 + br * 32 + 2 * mcol], b1 = wb[OFF_B3 + br * 32 + 2 * mcol + 1];
#pragma unroll
        for (int hr = 0; hr < 4; ++hr) {
            acc0[hr] = f32x4{b0, b0, b0, b0};
            acc1[hr] = f32x4{b1, b1, b1, b1};
        }
    }
    for (int kh = 0; kh < 3; ++kh) {
        const unsigned short* wbase = wf3 + kh * 3 * 1024 + lane * 8;
#pragma unroll
        for (int u = 0; u < 3; ++u) {
            bf16x8 bf0 = *(const bf16x8*)(wbase + u * 1024);
            bf16x8 bf1 = *(const bf16x8*)(wbase + u * 1024 + 512);
#pragma unroll
            for (int hr = 0; hr < 4; ++hr) {
                bf16x8 a = *(const bf16x8*)(&sIn[kh + hr][wave * 16 + mcol + u][q * 8]);
                acc0[hr] = __builtin_amdgcn_mfma_f32_16x16x32_bf16(a, bf0, acc0[hr], 0, 0, 0);
                acc1[hr] = __builtin_amdgcn_mfma_f32_16x16x32_bf16(a, bf1, acc1[hr], 0, 0, 0);
            }
        }
    }
#pragma unroll
    for (int hr = 0; hr < 4; ++hr) {
        int sh = h0 + hr - 4; if (sh < 0) sh += 384;
#pragma unroll
        for (int r = 0; r < 4; ++r) {
            int w = w0 + wave * 16 + q * 4 + r;
            int sw = w - 4; if (sw < 0) sw += 384;
            int win = (sh >> 3) * 48 + (sw >> 3);
            int tok = (sh & 7) * 8 + (sw & 7);
            unsigned tb = (unsigned)((b * 2304 + win) * 64 + tok) * 32u;
            *(unsigned*)(&qkv[tb + 2u * mcol]) = pk2bf(acc0[hr][r] * scale, acc1[hr][r] * scale);
        }
    }
}

// ---------- MFMA windowed attention: block=(win,b), wave=head (r10, 32-bit addr) ----------
__global__ __launch_bounds__(256) void attn_mfma(
    const unsigned short* __restrict__ Qp, const unsigned short* __restrict__ Kp,
    const unsigned short* __restrict__ Vp, const unsigned short* __restrict__ biasTb,
    unsigned short* __restrict__ att) {
    __shared__ __align__(16) unsigned short sVT[4][16][72];  // [head][dim(8=ones)][key]
    __shared__ __align__(16) unsigned short sPm[4][16][72];  // [head][q-row][key]
    __shared__ __align__(16) unsigned short sOut[64][40];    // [tok][ch32]
    const int win = blockIdx.x, b = blockIdx.y;
    const int wr = win / 48, wc = win % 48;
    const int tid = threadIdx.x;
    const int lane = tid & 63, head = tid >> 6;
    const unsigned wbase = (unsigned)(b * 2304 + win) * 64u;
    {
        int tok = lane;
        uint4 v = *(const uint4*)(Vp + (wbase + tok) * 32u + head * 8);
        unsigned short d[8];
        d[0] = (unsigned short)v.x; d[1] = (unsigned short)(v.x >> 16);
        d[2] = (unsigned short)v.y; d[3] = (unsigned short)(v.y >> 16);
        d[4] = (unsigned short)v.z; d[5] = (unsigned short)(v.z >> 16);
        d[6] = (unsigned short)v.w; d[7] = (unsigned short)(v.w >> 16);
#pragma unroll
        for (int dd = 0; dd < 8; ++dd) sVT[head][dd][tok] = d[dd];
        sVT[head][8][tok] = 0x3f80;   // 1.0 (ones column -> rowsum)
#pragma unroll
        for (int dd = 9; dd < 16; ++dd) sVT[head][dd][tok] = 0;
    }
    const int mcol = lane & 15, q = lane >> 4;
    const int cls = (wr == 47 ? 1 : 0) + (wc == 47 ? 2 : 0);
    const unsigned short* bT = biasTb + cls * 4096;
    const bf16x8 zero8 = {0, 0, 0, 0, 0, 0, 0, 0};
    bf16x8 kb[4];
#pragma unroll
    for (int nt = 0; nt < 4; ++nt)
        kb[nt] = (q == 0) ? *(const bf16x8*)(Kp + (wbase + nt * 16 + mcol) * 32u + head * 8) : zero8;
    bf16x8 vb0 = *(const bf16x8*)(&sVT[head][mcol][q * 8]);
    bf16x8 vb1 = *(const bf16x8*)(&sVT[head][mcol][32 + q * 8]);
#pragma unroll
    for (int mt = 0; mt < 4; ++mt) {
        bf16x8 qa = (q == 0) ? *(const bf16x8*)(Qp + (wbase + mt * 16 + mcol) * 32u + head * 8) : zero8;
        f32x4 s[4];
#pragma unroll
        for (int nt = 0; nt < 4; ++nt) {
            const ushort4 bb = *(const ushort4*)(bT + (nt * 16 + mcol) * 64 + mt * 16 + q * 4);
            s[nt] = f32x4{bf2f(bb.x), bf2f(bb.y), bf2f(bb.z), bf2f(bb.w)};
            s[nt] = __builtin_amdgcn_mfma_f32_16x16x32_bf16(qa, kb[nt], s[nt], 0, 0, 0);
        }
#pragma unroll
        for (int nt = 0; nt < 4; ++nt)
#pragma unroll
            for (int r = 0; r < 4; ++r) {
                float p = exp2f(fminf(s[nt][r], 86.f));  // masked bias -1e30 -> 0
                sPm[head][q * 4 + r][nt * 16 + mcol] = f2bf(p);
            }
        bf16x8 ap0 = *(const bf16x8*)(&sPm[head][mcol][q * 8]);
        bf16x8 ap1 = *(const bf16x8*)(&sPm[head][mcol][32 + q * 8]);
        f32x4 o = {0.f, 0.f, 0.f, 0.f};
        o = __builtin_amdgcn_mfma_f32_16x16x32_bf16(ap0, vb0, o, 0, 0, 0);
        o = __builtin_amdgcn_mfma_f32_16x16x32_bf16(ap1, vb1, o, 0, 0, 0);
#pragma unroll
        for (int r = 0; r < 4; ++r) {
            float sum = __shfl(o[r], (lane & 48) + 8, 64);
            float val = o[r] / sum;
            if (mcol < 8) {
                int tok = mt * 16 + q * 4 + r;
                sOut[tok][head * 8 + mcol] = f2bf(val);
            }
        }
    }
    __syncthreads();   // cross-wave: sOut columns come from all 4 heads
    {
        int tok = tid >> 2, seg = tid & 3;
        int ihh = tok >> 3, iww = tok & 7;
        int px = (wr * 8 + ihh) * 384 + wc * 8 + iww;
        uint4 pk = *(const uint4*)(&sOut[tok][seg * 8]);
        *(uint4*)(att + (((unsigned)(b * 147456 + px)) << 5) + seg * 8) = pk;
    }
}

// ---------- out conv MFMA (shifted space, NHWC32 in) + inverse roll + residual ----------
__global__ __launch_bounds__(256) void outconv_mfma(
    const unsigned short* __restrict__ att, const unsigned short* __restrict__ x_raw,
    const unsigned short* __restrict__ wf, const float* __restrict__ wb,
    void* __restrict__ outp, const int* __restrict__ flagp) {
    __shared__ __align__(16) unsigned short sIn[6][66][40];
    const int f32 = *flagp;
    const int b = blockIdx.z, h0 = blockIdx.y * 4, w0 = blockIdx.x * 64;
    const int tid = threadIdx.x;
    for (int idx = tid; idx < 1584; idx += 256) {
        int seg = idx & 3, t = idx >> 2, col = t % 66, kr = t / 66;
        int gh = h0 + kr - 1, gw = w0 + col - 1;
        uint4 v = make_uint4(0, 0, 0, 0);
        if ((unsigned)gh < 384u && (unsigned)gw < 384u)
            v = *(const uint4*)(att + (((unsigned)(b * 147456 + gh * 384 + gw)) << 5) + seg * 8);
        *(uint4*)(&sIn[kr][col][seg * 8]) = v;
    }
    __syncthreads();
    const int lane = tid & 63, wave = tid >> 6;
    const int mcol = lane & 15, q = lane >> 4;
    float bn = (mcol < 3) ? wb[OFF_BO + mcol] : 0.f;
    f32x4 acc[4];
#pragma unroll
    for (int hr = 0; hr < 4; ++hr) acc[hr] = f32x4{bn, bn, bn, bn};
    for (int kh = 0; kh < 3; ++kh) {
        const unsigned short* wbase = wf + kh * 3 * 512 + lane * 8;
#pragma unroll
        for (int u = 0; u < 3; ++u) {
            bf16x8 bf = *(const bf16x8*)(wbase + u * 512);
#pragma unroll
            for (int hr = 0; hr < 4; ++hr) {
                bf16x8 a = *(const bf16x8*)(&sIn[kh + hr][wave * 16 + mcol + u][q * 8]);
                acc[hr] = __builtin_amdgcn_mfma_f32_16x16x32_bf16(a, bf, acc[hr], 0, 0, 0);
            }
        }
    }
    if (mcol < 3) {
#pragma unroll
        for (int hr = 0; hr < 4; ++hr) {
            int oh = h0 + hr + 4; if (oh >= 384) oh -= 384;
#pragma unroll
            for (int r = 0; r < 4; ++r) {
                int w = w0 + wave * 16 + q * 4 + r;
                int ow = w + 4; if (ow >= 384) ow -= 384;
                unsigned idx = (unsigned)(b * 3 + mcol) * 147456u + oh * 384 + ow;
                float xv = loadEl(x_raw, (long)idx, f32);
                float o = acc[hr][r] + xv;
                if (f32) ((float*)outp)[idx] = o;
                else ((unsigned short*)outp)[idx] = f2bf(o);
            }
        }
    }
}

extern "C" void kernel_launch(void* const* d_in, const int* in_sizes, int n_in,
                              void* d_out, int out_size, void* d_ws, size_t ws_size,
                              hipStream_t stream) {
    Ptrs P;
    for (int i = 0; i < 22; ++i) P.p[i] = (const unsigned short*)d_in[i];
    const unsigned short* x_raw = (const unsigned short*)d_in[0];

    char* ws = (char*)d_ws;
    float* wb = (float*)ws;
    int* flag = (int*)(ws + 448 * 1024);
    unsigned short* wf = (unsigned short*)(ws + 512 * 1024);
    unsigned short* xc = (unsigned short*)(ws + 1024 * 1024);
    unsigned short* h2all = (unsigned short*)(ws + 3670016);          // 3 br x 18.9MB
    unsigned short* qkvAll = (unsigned short*)(ws + 3670016 + (size_t)3 * H2SZ * 2);
    unsigned short* att = h2all;   // alias: h2 dead after conv3

    prep_kern<<<dim3(1024), dim3(256), 0, stream>>>(P, wb, wf, xc, flag);
    conv12_mfma<<<dim3(6, 192, 6), dim3(256), 0, stream>>>(xc, wf, wb, h2all);
    conv3_mfma<<<dim3(6, 96, 6), dim3(256), 0, stream>>>(h2all, wf, wb, qkvAll);
    attn_mfma<<<dim3(2304, 2), dim3(256), 0, stream>>>(
        qkvAll, qkvAll + H2SZ, qkvAll + 2 * (size_t)H2SZ, wf + OFFBT, att);
    outconv_mfma<<<dim3(6, 96, 2), dim3(256), 0, stream>>>(att, x_raw, wf + OFFWO,
                                                           wb, d_out, flag);
}